// Round 5
// baseline (221.086 us; speedup 1.0000x reference)
//
#include <hip/hip_runtime.h>
#include <math.h>

// NuclearLoss: cls_score (8,19,512,512) fp32 -> scalar fp32.
// loss = -(1/B) * sum over patches,channels of sqrt( sum_pixels softmax(x)[c]^2 )
// B = 8 * 32 * 32 = 8192 patches of 16x16.

#define NIMG 8
#define CCH  19
#define HH   512
#define WW   512
#define CHST (HH * WW)          // channel stride in floats (262144 = 1MB)

// DPP-based add: x + (x shuffled by CTRL). Full-rate VALU, no LDS pipe.
template <int CTRL>
__device__ __forceinline__ float dpp_add(float x) {
    int t = __builtin_amdgcn_update_dpp(0, __float_as_int(x), CTRL, 0xF, 0xF, true);
    return x + __int_as_float(t);
}

typedef __attribute__((address_space(1))) const unsigned int gbuf_t;
typedef __attribute__((address_space(3))) unsigned int lbuf_t;

// The 1MB channel stride aliases L1 sets, L2 sets and HBM channel bits: a
// wave's 19 concurrent channel loads all land in ONE set/channel class ->
// per-wave MLP collapses (kernel measured ~2.4 TB/s, 37% of achievable).
// Fix: for channel c, lane g sources pixel-group h = g ^ ((c&15)<<2) (XOR on
// the r/p lane fields -> address bits 6-7 and 11-12 vary per channel -> 8
// line/set/channel classes instead of 1). global_load_lds writes linearly at
// lane*16; the compute-side ds_read at (g^x)*16 un-permutes FOR FREE
// (swizzled-global-source + linear-LDS, the m173-verified pattern).
__global__ __launch_bounds__(256, 4) void nuclear_loss_kernel(
    const float* __restrict__ in, float* __restrict__ out) {
    __shared__ __align__(16) float stage[4][8][256];  // 4 waves x 8 slots x 1KB
    __shared__ float psum[4 * 4 * CCH];  // [wave][patch][channel]
    __shared__ float total;

    const int tid  = threadIdx.x;
    const int b    = blockIdx.x;
    const int n    = b >> 8;        // 256 blocks per image
    const int rem  = b & 255;
    const int prow = rem >> 3;      // patch row 0..31
    const int creg = rem & 7;       // 64-col region 0..7
    const int w    = tid >> 6;      // wave 0..3
    const int g    = tid & 63;
    const int p    = g >> 4;        // patch within region 0..3
    const int r    = (g >> 2) & 3;  // row within wave's 4-row band
    const int cq   = g & 3;         // col-group within patch 0..3

    if (tid == 0) total = 0.0f;

    // Wave footprint: rows prow*16+4w..+3, cols creg*64..+63 (per channel).
    const float* wbase = in + (size_t)n * (size_t)(CCH * CHST)
                            + (size_t)((prow << 4) + (w << 2)) * WW
                            + (creg << 6);

    // Issue one 1KB global_load_lds for channel c into ring slot s.
    // Lane g sources pixel-group h = g ^ x(c); off(h) decodes h's (r,p,cq).
#define ISSUE(c, s)                                                            \
    do {                                                                       \
        const int h_  = g ^ (((c) & 15) << 2);                                 \
        const int off = (((h_ >> 2) & 3) * WW) + (((h_ >> 4) & 3) << 4)        \
                        + ((h_ & 3) << 2);                                     \
        __builtin_amdgcn_global_load_lds(                                      \
            (gbuf_t*)(wbase + (size_t)(c) * CHST + off),                       \
            (lbuf_t*)&stage[w][s][0], 16, 0, 0);                               \
    } while (0)

    // Read channel c back from slot s, un-permuting via the same XOR.
#define READC(c, s)                                                            \
    v[c] = *reinterpret_cast<const float4*>(                                   \
        &stage[w][s][(g ^ (((c) & 15) << 2)) << 2])

#define WAITVM(N) asm volatile("s_waitcnt vmcnt(" #N ")" ::: "memory")
#define DRAINLGKM() asm volatile("s_waitcnt lgkmcnt(0)" ::: "memory")

    float4 v[CCH];
    // 5 chunks of {4,4,4,4,3}, ring of 8 slots, 2 chunks in flight (counted
    // vmcnt, never drained to 0 mid-loop). lgkmcnt(0) before each slot reuse
    // guards the ds_read-vs-incoming-LDS-write WAR hazard.
    ISSUE(0, 0); ISSUE(1, 1); ISSUE(2, 2); ISSUE(3, 3);      // chunk0
    ISSUE(4, 4); ISSUE(5, 5); ISSUE(6, 6); ISSUE(7, 7);      // chunk1
    WAITVM(4);                                               // chunk0 landed
    READC(0, 0); READC(1, 1); READC(2, 2); READC(3, 3);
    DRAINLGKM();
    ISSUE(8, 0); ISSUE(9, 1); ISSUE(10, 2); ISSUE(11, 3);    // chunk2
    WAITVM(4);                                               // chunk1 landed
    READC(4, 4); READC(5, 5); READC(6, 6); READC(7, 7);
    DRAINLGKM();
    ISSUE(12, 4); ISSUE(13, 5); ISSUE(14, 6); ISSUE(15, 7);  // chunk3
    WAITVM(4);                                               // chunk2 landed
    READC(8, 0); READC(9, 1); READC(10, 2); READC(11, 3);
    DRAINLGKM();
    ISSUE(16, 0); ISSUE(17, 1); ISSUE(18, 2);                // chunk4
    WAITVM(3);                                               // chunk3 landed
    READC(12, 4); READC(13, 5); READC(14, 6); READC(15, 7);
    WAITVM(0);                                               // chunk4 landed
    READC(16, 0); READC(17, 1); READC(18, 2);

    // Softmax denominators for the thread's 4 pixels (no max-subtraction:
    // inputs ~N(0,1), exp stays well inside fp32).
    float sx = 0.f, sy = 0.f, sz = 0.f, sw = 0.f;
#pragma unroll
    for (int c = 0; c < CCH; ++c) {
        v[c].x = __expf(v[c].x); sx += v[c].x;
        v[c].y = __expf(v[c].y); sy += v[c].y;
        v[c].z = __expf(v[c].z); sz += v[c].z;
        v[c].w = __expf(v[c].w); sw += v[c].w;
    }
    const float ix = __builtin_amdgcn_rcpf(sx);
    const float iy = __builtin_amdgcn_rcpf(sy);
    const float iz = __builtin_amdgcn_rcpf(sz);
    const float iw = __builtin_amdgcn_rcpf(sw);

    const bool lead = ((g & 15) == 12);  // lanes 12+16k hold the 16-lane sum

#pragma unroll
    for (int c = 0; c < CCH; ++c) {
        const float tx = v[c].x * ix;
        const float ty = v[c].y * iy;
        const float tz = v[c].z * iz;
        const float tw = v[c].w * iw;
        float x = tx * tx;
        x = fmaf(ty, ty, x);
        x = fmaf(tz, tz, x);
        x = fmaf(tw, tw, x);
        // 16-lane reduce, all VALU: quads, then quad-sums 4 and 8 apart.
        x = dpp_add<0xB1>(x);    // quad_perm[1,0,3,2]
        x = dpp_add<0x4E>(x);    // quad_perm[2,3,0,1]
        x = dpp_add<0x114>(x);   // row_shr:4
        x = dpp_add<0x118>(x);   // row_shr:8
        if (lead)
            psum[(w << 2 | p) * CCH + c] = x;
    }
    __syncthreads();

    // 76 per-(patch,channel) diag entries = sum of 4 wave partials; sqrt; reduce.
    if (tid < 128) {
        float acc = 0.0f;
        if (tid < 4 * CCH) {
            const float s4 = psum[tid] + psum[76 + tid]
                           + psum[152 + tid] + psum[228 + tid];
            acc = sqrtf(s4);
        }
        acc += __shfl_down(acc, 32, 64);
        acc += __shfl_down(acc, 16, 64);
        acc += __shfl_down(acc, 8, 64);
        acc += __shfl_down(acc, 4, 64);
        acc += __shfl_down(acc, 2, 64);
        acc += __shfl_down(acc, 1, 64);
        if (g == 0) atomicAdd(&total, acc);   // 2 LDS atomics per block
    }
    __syncthreads();
    if (tid == 0) atomicAdd(out, total * (-1.0f / 8192.0f));
}

extern "C" void kernel_launch(void* const* d_in, const int* in_sizes, int n_in,
                              void* d_out, int out_size, void* d_ws, size_t ws_size,
                              hipStream_t stream) {
    const float* in = (const float*)d_in[0];
    float* out = (float*)d_out;
    // d_out is poisoned to 0xAA before every call; zero it (capturable memset node).
    hipMemsetAsync(out, 0, sizeof(float), stream);
    // 8 images * 32 patch-rows * 8 col-regions = 2048 blocks
    nuclear_loss_kernel<<<2048, 256, 0, stream>>>(in, out);
}